// Round 7
// baseline (207.830 us; speedup 1.0000x reference)
//
#include <hip/hip_runtime.h>
#include <hip/hip_bf16.h>

typedef __attribute__((ext_vector_type(8))) short bf16x8;
typedef __attribute__((ext_vector_type(16))) float f32x16;
typedef __attribute__((ext_vector_type(2))) unsigned u32x2;

// packed f32x2 -> bf16x2 (RNE)
__device__ __forceinline__ unsigned pk2(float a, float b) {
    union { __hip_bfloat162 h2; unsigned u; } c;
    c.h2 = __float22bfloat162_rn(make_float2(a, b));
    return c.u;
}

// async global->LDS DMA, 16 B/lane; LDS dest = wave-uniform base + lane*16
__device__ __forceinline__ void gld16(const void* g, void* l) {
    __builtin_amdgcn_global_load_lds(
        (const __attribute__((address_space(1))) unsigned*)g,
        (__attribute__((address_space(3))) unsigned*)l, 16, 0, 0);
}

// exact transcription of the reference _hilbert_index_to_xy; returns p = x*d + y
__device__ inline int hilbert_p(int index, int d) {
    int x = 0, y = 0;
    for (int s = 1; s < d; s <<= 1) {
        int rx = (index >> 1) & 1;
        int ry = (index ^ rx) & 1;
        if (ry == 0) {
            if (rx == 1) {
                int nx = s - 1 - y;
                int ny = s - 1 - x;
                x = nx; y = ny;
            }
            int t = x; x = y; y = t;
        }
        x += s * rx;
        y += s * ry;
        index >>= 2;
    }
    return x * d + y;
}

// One block per 64-key tile (1120 tiles total: g0=640, g1=320, g2=160).
//
// R7 REWRITE: barrier-free, LDS-free, deep ILP. The old version had 2
// work-items/thread (shallow ILP over ~900-cyc scattered loads), a block
// barrier, and a V transpose through LDS (scalar ds_read_u16 on the way
// out) — a serial load->LDS->load->store chain. It cost ~100 us vs a
// ~10-15 us roofline (reads ~37 MB, writes 18.4 MB).
// Now:
//  - wave 0 (threads 0-63): V transpose fully IN REGISTERS. Thread owns an
//    (8 keys x 8 dims) micro-tile: 16 independent float4 loads in flight,
//    the bf16 pack (pk2 of key-pairs) IS the transpose, 8 contiguous 16 B
//    stores. No LDS, no barrier.
//  - waves 1-3 (threads 64-255): K copy/convert (2-3 items each, as before).
// Chunk-linear layouts (R6, unchanged — attn passes on them):
//   kchunk(j,c8)  = ((j>>5)*4 + (c8>>1))*64 + (c8&1)*32 + (j&31)
//   vchunk(dd,k8) = ((k8>>1)*2 + (dd>>5))*64 + (k8&1)*32 + (dd&31)
__global__ __launch_bounds__(256, 4) void gather_kv(
    const float* __restrict__ K, const float* __restrict__ V,
    short* __restrict__ Kp, short* __restrict__ Vp)
{
    const int b = blockIdx.x;
    int g, rb;
    if (b < 640)      { g = 0; rb = b; }
    else if (b < 960) { g = 1; rb = b - 640; }
    else              { g = 2; rb = b - 960; }
    const int nseg   = 4 >> g;
    const int hl     = rb / (nseg * 32);
    const int r2     = rb - hl * (nseg * 32);
    const int seg    = r2 >> 5;
    const int kt     = r2 & 31;
    const int h      = g * 5 + hl;
    const int S      = 2048 << g;
    const int segrow = seg * S;
    const int dgrid  = (g == 2) ? 128 : 64;
    const size_t tile_s = (size_t)b * 4096;   // tile base in shorts (8 KB/tile)

    const int tid = threadIdx.x;

    if (tid < 64) {
        // ---- V path: (8 keys x 8 dims) micro-tile per thread, in-register
        // transpose. k8 = key-octet, d8 = dim-octet.
        const int k8 = tid >> 3;
        const int d8 = tid & 7;
        float rowf[8][8];   // [key-in-octet][dim-in-octet], statically indexed
#pragma unroll
        for (int u = 0; u < 8; ++u) {
            const int j  = k8 * 8 + u;
            const int ii = kt * 64 + j;
            const int p  = (g == 0) ? ii : hilbert_p(ii << g, dgrid);
            const float* vp = V + ((size_t)((segrow + p) * 16 + h)) * 64 + d8 * 8;
            float4 a = ((const float4*)vp)[0];
            float4 bq = ((const float4*)vp)[1];
            rowf[u][0] = a.x;  rowf[u][1] = a.y;  rowf[u][2] = a.z;  rowf[u][3] = a.w;
            rowf[u][4] = bq.x; rowf[u][5] = bq.y; rowf[u][6] = bq.z; rowf[u][7] = bq.w;
        }
#pragma unroll
        for (int w = 0; w < 8; ++w) {
            const int dd = d8 * 8 + w;
            union { unsigned u4[4]; bf16x8 v; } o;
            o.u4[0] = pk2(rowf[0][w], rowf[1][w]);
            o.u4[1] = pk2(rowf[2][w], rowf[3][w]);
            o.u4[2] = pk2(rowf[4][w], rowf[5][w]);
            o.u4[3] = pk2(rowf[6][w], rowf[7][w]);
            const int vchunk = ((k8 >> 1) * 2 + (dd >> 5)) * 64 + (k8 & 1) * 32 + (dd & 31);
            *(bf16x8*)&Vp[tile_s + vchunk * 8] = o.v;
        }
    } else {
        // ---- K path: 512 (row, dim-octet) items over 192 threads
        for (int it = tid - 64; it < 512; it += 192) {
            const int j  = it >> 3;
            const int c8 = it & 7;
            const int ii = kt * 64 + j;
            const int p  = (g == 0) ? ii : hilbert_p(ii << g, dgrid);
            const float* kp = K + ((size_t)((segrow + p) * 16 + h)) * 64 + c8 * 8;
            float4 k0 = ((const float4*)kp)[0];
            float4 k1 = ((const float4*)kp)[1];
            union { unsigned u4[4]; bf16x8 v; } ck;
            ck.u4[0] = pk2(k0.x, k0.y); ck.u4[1] = pk2(k0.z, k0.w);
            ck.u4[2] = pk2(k1.x, k1.y); ck.u4[3] = pk2(k1.z, k1.w);
            const int kchunk = ((j >> 5) * 4 + (c8 >> 1)) * 64 + (c8 & 1) * 32 + (j & 31);
            *(bf16x8*)&Kp[tile_s + kchunk * 8] = ck.v;
        }
    }
}

// One block = (group g, head hl, 128-query tile). 4 waves, 32 queries/wave.
// R6 attn, UNCHANGED (clean A/B vs gather rewrite): 32x32x16 MFMA,
// in-register P via cvt_pk + permlane32_swap, software pipeline with
// double-buffered LDS K/V, counted vmcnt(4), 2 barriers/tile, LDS 32 KB,
// zero bank conflicts.
__global__ __launch_bounds__(256, 4) void attn_kernel(
    const float* __restrict__ Q, float* __restrict__ O,
    const short* __restrict__ Kp, const short* __restrict__ Vp)
{
    __shared__ __align__(16) short ldsK[2][4096];  // 2 x 8 KB, chunk-linear
    __shared__ __align__(16) short ldsV[2][4096];  // 2 x 8 KB, chunk-linear

    const int bx = blockIdx.x;
    const int g  = bx / 320;
    const int r  = bx - g * 320;
    const int hl = r >> 6;
    const int qb = r & 63;
    const int h  = g * 5 + hl;
    const int qglob = qb * 128;
    const int seg   = qb >> (4 + g);
    const int tile0 = ((g == 0) ? 0 : (g == 1) ? 640 : 960) + (hl * (4 >> g) + seg) * 32;

    const int tid  = threadIdx.x;
    const int wave = tid >> 6;
    const int lane = tid & 63;
    const int l31  = lane & 31;
    const int hi   = lane >> 5;

    // head 15 belongs to no group: zero it here (d_out is poisoned each run).
    if (g == 0 && hl == 0) {
        const float4 z = make_float4(0.f, 0.f, 0.f, 0.f);
        for (int i = tid; i < 2048; i += 256) {
            int row = qglob + (i >> 4);
            ((float4*)O)[(size_t)(row * 16 + 15) * 16 + (i & 15)] = z;
        }
    }

    // ---- Q fragments (B-operand of S^T = K.Q^T, 32x32x16):
    // lane holds Q[q = base + l31][dims 16ks + 8hi .. +8], pre-scaled
    const float cs = 0.125f * 1.44269504088896f;   // scale * log2(e)
    bf16x8 qf[4];
    {
        const int qrow = qglob + wave * 32 + l31;
        const float* qp = Q + ((size_t)(qrow * 16 + h)) * 64;
#pragma unroll
        for (int ks = 0; ks < 4; ++ks) {
            const float4* p4 = (const float4*)(qp + ks * 16 + hi * 8);
            float4 a = p4[0], b = p4[1];
            union { unsigned u[4]; bf16x8 v; } f;
            f.u[0] = pk2(a.x * cs, a.y * cs); f.u[1] = pk2(a.z * cs, a.w * cs);
            f.u[2] = pk2(b.x * cs, b.y * cs); f.u[3] = pk2(b.z * cs, b.w * cs);
            qf[ks] = f.v;
        }
    }

    f32x16 oacc[2];
#pragma unroll
    for (int rr = 0; rr < 16; ++rr) { oacc[0][rr] = 0.f; oacc[1][rr] = 0.f; }
    float lp = 0.f;

    const int lbase = lane * 8;   // fragment base in shorts (lane*16 B)

    // ---- prologue: stage tile 0 into buffer 0
    {
        const size_t tb = (size_t)tile0 << 13;   // 8 KB per tile
        const char* kgp = (const char*)Kp + tb + (wave << 11) + (lane << 4);
        const char* vgp = (const char*)Vp + tb + (wave << 11) + (lane << 4);
        char* klp = (char*)&ldsK[0][0] + (wave << 11);
        char* vlp = (char*)&ldsV[0][0] + (wave << 11);
        gld16(kgp,        klp);
        gld16(kgp + 1024, klp + 1024);
        gld16(vgp,        vlp);
        gld16(vgp + 1024, vlp + 1024);
    }

    for (int kt = 0; kt < 32; ++kt) {
        const int cur = kt & 1;
        // ---- issue next tile's staging DMAs, then counted wait for the
        // current tile's 4 DMAs (issued one iteration ago).
        if (kt < 31) {
            const size_t tb = (size_t)(tile0 + kt + 1) << 13;
            const char* kgp = (const char*)Kp + tb + (wave << 11) + (lane << 4);
            const char* vgp = (const char*)Vp + tb + (wave << 11) + (lane << 4);
            char* klp = (char*)&ldsK[cur ^ 1][0] + (wave << 11);
            char* vlp = (char*)&ldsV[cur ^ 1][0] + (wave << 11);
            gld16(kgp,        klp);
            gld16(kgp + 1024, klp + 1024);
            gld16(vgp,        vlp);
            gld16(vgp + 1024, vlp + 1024);
            asm volatile("s_waitcnt vmcnt(4)" ::: "memory");
        } else {
            asm volatile("s_waitcnt vmcnt(0)" ::: "memory");
        }
        asm volatile("s_barrier" ::: "memory");   // current tile visible to all waves

        const short* lK = &ldsK[cur][lbase];
        const short* lV = &ldsV[cur][lbase];

        // ---- S-phase: per 32-key block kb: S^T = K.Q^T (4 k-steps of 16 dims),
        // exp2, pack to bf16 dwords. Lane holds S^T[key m(reg,hi)+32kb][q=l31],
        // m(reg,hi) = (reg&3) + 8*(reg>>2) + 4*hi.
        float lacc = 0.f;
        unsigned dw[16];   // dw[ks*4 + j*2 + hT]; j = dword-pair, hT = target hi
        __builtin_amdgcn_s_setprio(1);
#pragma unroll
        for (int kb = 0; kb < 2; ++kb) {
            bf16x8 kf0 = *(const bf16x8*)&lK[(kb * 4 + 0) * 512];
            bf16x8 kf1 = *(const bf16x8*)&lK[(kb * 4 + 1) * 512];
            bf16x8 kf2 = *(const bf16x8*)&lK[(kb * 4 + 2) * 512];
            bf16x8 kf3 = *(const bf16x8*)&lK[(kb * 4 + 3) * 512];
            f32x16 sa;
#pragma unroll
            for (int rr = 0; rr < 16; ++rr) sa[rr] = 0.f;
            sa = __builtin_amdgcn_mfma_f32_32x32x16_bf16(kf0, qf[0], sa, 0, 0, 0);
            sa = __builtin_amdgcn_mfma_f32_32x32x16_bf16(kf1, qf[1], sa, 0, 0, 0);
            sa = __builtin_amdgcn_mfma_f32_32x32x16_bf16(kf2, qf[2], sa, 0, 0, 0);
            sa = __builtin_amdgcn_mfma_f32_32x32x16_bf16(kf3, qf[3], sa, 0, 0, 0);
            float pe[16];
#pragma unroll
            for (int rr = 0; rr < 16; ++rr) pe[rr] = __builtin_amdgcn_exp2f(sa[rr]);
            lacc += (((pe[0] + pe[1]) + (pe[2] + pe[3])) + ((pe[4] + pe[5]) + (pe[6] + pe[7])))
                  + (((pe[8] + pe[9]) + (pe[10] + pe[11])) + ((pe[12] + pe[13]) + (pe[14] + pe[15])));
            // dword for (ks, t, hT): keys 16ks + 8hT + 2t,+1 come from regs
            // r0 = 2(t&1) + 8(ks&1) + 4hT in lanes with hi == t>>1.
#pragma unroll
            for (int kslo = 0; kslo < 2; ++kslo)
#pragma unroll
                for (int j = 0; j < 2; ++j)
#pragma unroll
                    for (int hT = 0; hT < 2; ++hT) {
                        const int r0 = 2 * j + 8 * kslo + 4 * hT;
                        dw[(kb * 2 + kslo) * 4 + j * 2 + hT] = pk2(pe[r0], pe[r0 + 1]);
                    }
        }
        __builtin_amdgcn_s_setprio(0);
        lp += lacc;

        // ---- assemble PV A-frags: pa[ks] = P[q=l31][keys 16ks + 8hi .. +8].
        bf16x8 pa[4];
#pragma unroll
        for (int ks = 0; ks < 4; ++ks) {
            u32x2 r0 = __builtin_amdgcn_permlane32_swap(dw[ks * 4 + 0], dw[ks * 4 + 1], false, false);
            u32x2 r1 = __builtin_amdgcn_permlane32_swap(dw[ks * 4 + 2], dw[ks * 4 + 3], false, false);
            union { unsigned u[4]; bf16x8 v; } p;
            p.u[0] = r0[0]; p.u[1] = r1[0]; p.u[2] = r0[1]; p.u[3] = r1[1];
            pa[ks] = p.v;
        }

        // keep vf loads out of the kf/sacc live range (R2 spill lesson)
        __builtin_amdgcn_sched_barrier(0);

        // ---- V B-fragments: lane holds V[keys 16ks+8hi..+8][dim = 32db+l31]
        bf16x8 vf[4][2];
#pragma unroll
        for (int ks = 0; ks < 4; ++ks)
#pragma unroll
            for (int db = 0; db < 2; ++db)
                vf[ks][db] = *(const bf16x8*)&lV[(ks * 2 + db) * 512];

        // ---- PV: O[q][dim] += P.V over 4 key-blocks of 16
        __builtin_amdgcn_s_setprio(1);
#pragma unroll
        for (int ks = 0; ks < 4; ++ks) {
            oacc[0] = __builtin_amdgcn_mfma_f32_32x32x16_bf16(pa[ks], vf[ks][0], oacc[0], 0, 0, 0);
            oacc[1] = __builtin_amdgcn_mfma_f32_32x32x16_bf16(pa[ks], vf[ks][1], oacc[1], 0, 0, 0);
        }
        __builtin_amdgcn_s_setprio(0);

        asm volatile("s_barrier" ::: "memory");   // all reads of buf[cur] done
                                                  // before next iter's DMA overwrites it
    }

    // ---- l: lane pair (l31, hi=0/1) each hold half the key-sum for q=l31
    float ltot = lp + __shfl_xor(lp, 32, 64);
    float linv = 1.0f / ltot;

    // ---- epilogue: O / l. C-layout: col = dim-in-block = l31,
    // row = q = (reg&3) + 8*(reg>>2) + 4*hi.
#pragma unroll
    for (int rr = 0; rr < 16; ++rr) {
        const int m = (rr & 3) + ((rr >> 2) << 3) + (hi << 2);
        float inv = __shfl(linv, m, 64);   // linv for q=m lives at lane m
        const int qrow = qglob + wave * 32 + m;
        float* op = O + ((size_t)(qrow * 16 + h)) * 64 + l31;
        op[0]  = oacc[0][rr] * inv;
        op[32] = oacc[1][rr] * inv;
    }
}

extern "C" void kernel_launch(void* const* d_in, const int* in_sizes, int n_in,
                              void* d_out, int out_size, void* d_ws, size_t ws_size,
                              hipStream_t stream) {
    const float* q = (const float*)d_in[0];
    const float* k = (const float*)d_in[1];
    const float* v = (const float*)d_in[2];
    float* out = (float*)d_out;
    short* Kp = (short*)d_ws;                       // 1120 tiles * 8 KB = 9.18 MB
    short* Vp = Kp + (size_t)1120 * 4096;           // + 9.18 MB  (ws total ~18.4 MB)

    gather_kv<<<1120, 256, 0, stream>>>(k, v, Kp, Vp);
    attn_kernel<<<960, 256, 0, stream>>>(q, out, Kp, Vp);
}